// Round 5
// baseline (12403.725 us; speedup 1.0000x reference)
//
#include <hip/hip_runtime.h>

#define I_DIMM 256
#define H_DIMM 1024
#define O_DIMM 256
#define S_LENN 512
#define B_SZZ  64
#define SBB    (S_LENN*B_SZZ)      // 32768
#define NKT    40                  // k-tiles of 32 over K=1280
#define NTILE  68                  // 64 gate tiles + 4 fc tiles (64 rows each)

typedef float f32x4  __attribute__((ext_vector_type(4)));
typedef short short8 __attribute__((ext_vector_type(8)));

// ws layout (bytes):
#define OFF_ABF 0u                  // A frags: 68*40*4*64*16 = 11,141,120
#define OFF_BX  11141120u           // X frags: 512*8*4*64*16 = 16,777,216
#define OFF_HB0 27918336u           // h frag bufs x3: 131,072 each
#define OFF_HB1 28049408u
#define OFF_HB2 28180480u
#define OFF_C   28311552u           // c state f32: 262,144
#define OFF_HF  28573696u           // final h f32: 262,144
#define OFF_BAR 28835840u           // barrier: cnt @0, sense @64

__device__ __forceinline__ float sigm(float x){ return 1.f/(1.f+__expf(-x)); }
__device__ __forceinline__ float tanh_fast(float x){
  x = fminf(fmaxf(x,-15.f),15.f);
  float e = __expf(2.f*x);
  return (e-1.f)/(e+1.f);
}
__device__ __forceinline__ unsigned short f2bf(float x){
  unsigned u = __float_as_uint(x);
  u += 0x7FFFu + ((u>>16)&1u);            // RNE
  return (unsigned short)(u>>16);
}

// ---- pack weights into A-fragment layout (once per launch) ----
__global__ __launch_bounds__(256) void prep_w(
    const float* __restrict__ Wf, const float* __restrict__ Wi,
    const float* __restrict__ Wo, const float* __restrict__ Wc,
    const float* __restrict__ Uf, const float* __restrict__ Ui,
    const float* __restrict__ Uo, const float* __restrict__ Uc,
    const float* __restrict__ fcw, unsigned short* __restrict__ A_bf)
{
  int u = blockIdx.x*256 + threadIdx.x;          // 0 .. 696319
  int lane = u & 63;
  int mt   = (u >> 6) & 3;
  int kt   = (u >> 8) % NKT;
  int tile = u / (NKT*4*64);
  int r16  = lane & 15;
  int kb   = kt*32 + (lane>>4)*8;
  short8 v;
  if (tile < 64) {
    int zrow = tile*64 + mt*16 + r16;
    int h = zrow >> 2, g = zrow & 3;
    const float* Ws = (g==0)?Wf:(g==1)?Wi:(g==2)?Wo:Wc;
    const float* Us = (g==0)?Uf:(g==1)?Ui:(g==2)?Uo:Uc;
    #pragma unroll
    for (int j = 0; j < 8; ++j) {
      int k = kb + j;
      float x = (k < I_DIMM) ? Ws[h*I_DIMM + k] : Us[h*H_DIMM + (k - I_DIMM)];
      v[j] = (short)f2bf(x);
    }
  } else {
    int o = (tile-64)*64 + mt*16 + r16;
    #pragma unroll
    for (int j = 0; j < 8; ++j) {
      int k = kb + j;
      v[j] = (short)((k < I_DIMM) ? 0 : f2bf(fcw[o*H_DIMM + (k - I_DIMM)]));
    }
  }
  *(short8*)(A_bf + (size_t)u*8) = v;
}

// ---- pack X into B-fragment layout for all steps (once per launch) ----
__global__ __launch_bounds__(256) void prep_x(
    const float* __restrict__ X, unsigned short* __restrict__ Bx)
{
  int u = blockIdx.x*256 + threadIdx.x;          // 0 .. 1048575
  int lane = u & 63;
  int ct   = (u >> 6) & 3;
  int kt   = (u >> 8) & 7;
  int s    = u >> 11;
  int col  = ct*16 + (lane & 15);
  int kb   = kt*32 + (lane>>4)*8;
  short8 v;
  #pragma unroll
  for (int j = 0; j < 8; ++j)
    v[j] = (short)f2bf(X[(size_t)(kb + j)*SBB + s*B_SZZ + col]);
  *(short8*)(Bx + (size_t)u*8) = v;
}

// ---- persistent kernel: all 512 steps in one dispatch ----
// 68 blocks x 512 thr (8 waves, 2/SIMD). Wave w: ct=w&3, half=w>>2 ->
// mt {2*half, 2*half+1}. A even-mt kt<28 in VGPRs; odd-mt all kt + even-mt
// kt>=28 in LDS. c in registers. One device barrier per step; h triple-buf.
__global__ __launch_bounds__(512, 2) void lstm_persist(
    const unsigned short* __restrict__ A_bf,
    const unsigned short* __restrict__ Bx,
    unsigned short* __restrict__ hbuf0,
    unsigned short* __restrict__ hbuf1,
    unsigned short* __restrict__ hbuf2,
    const float* __restrict__ bfp, const float* __restrict__ bip,
    const float* __restrict__ bop, const float* __restrict__ bcp,
    const float* __restrict__ fcb,
    float* __restrict__ cbuf, float* __restrict__ hf,
    float* __restrict__ out, unsigned* __restrict__ bar)
{
  __shared__ short8 s_odd[NKT][2][64];   // odd-mt frags, all kt   (80 KB)
  __shared__ short8 s_et [12][2][64];    // even-mt frags, kt>=28  (24 KB)

  const int t    = blockIdx.x;
  const int tid  = threadIdx.x;
  const int lane = tid & 63;
  const int w    = tid >> 6;
  const int ct   = w & 3;
  const int half = w >> 2;
  const bool is_gate = (t < 64);
  const int col  = ct*16 + (lane & 15);

  const short8* Af = (const short8*)A_bf + (size_t)t*NKT*4*64;

  // stage LDS A frags
  for (int i = tid; i < 104*64; i += 512) {
    int a = i >> 6, l = i & 63;
    if (a < 80) { int kt = a >> 1, hh = a & 1;
      s_odd[kt][hh][l] = Af[(kt*4 + 2*hh + 1)*64 + l];
    } else { int e = a - 80; int kt = 28 + (e >> 1), hh = e & 1;
      s_et[kt-28][hh][l] = Af[(kt*4 + 2*hh)*64 + l];
    }
  }
  // even-mt kt 0..27 into registers
  short8 areg[28];
  #pragma unroll
  for (int kt = 0; kt < 28; ++kt)
    areg[kt] = Af[(kt*4 + 2*half)*64 + lane];
  __syncthreads();

  // s-invariant epilogue constants
  int   hh2[2]; size_t hoff[2];
  float bfr[2], bir[2], bor[2], bcr[2], fcbr[2][4];
  #pragma unroll
  for (int e = 0; e < 2; ++e) {
    int mt = 2*half + e;
    int h  = t*16 + mt*4 + (lane >> 4);
    hh2[e] = h;
    int kl = h & 31;
    hoff[e] = (size_t)((((h>>5)*4 + ct)*64 + (((kl>>3)<<4) | (lane & 15))))*8
              + (kl & 7);
    if (is_gate) { bfr[e]=bfp[h]; bir[e]=bip[h]; bor[e]=bop[h]; bcr[e]=bcp[h]; }
    else {
      #pragma unroll
      for (int r = 0; r < 4; ++r)
        fcbr[e][r] = fcb[(t-64)*64 + mt*16 + 4*(lane>>4) + r];
    }
  }

  unsigned short* hbs[3] = {hbuf0, hbuf1, hbuf2};
  float c0 = 0.f, c1 = 0.f;

  // prefetch x frags for s=0
  short8 bx_pf[8];
  if (is_gate) {
    #pragma unroll
    for (int kt = 0; kt < 8; ++kt)
      bx_pf[kt] = ((const short8*)Bx)[(kt*4 + ct)*64 + lane];
  }

  for (int s = 0; s <= S_LENN; ++s) {
    if (s == S_LENN && is_gate) break;          // gates done after barrier 511
    const short8* Bh = (const short8*)hbs[s % 3];
    unsigned short* hwr = hbs[(s + 1) % 3];
    f32x4 acc0 = {0.f,0.f,0.f,0.f}, acc1 = {0.f,0.f,0.f,0.f};

    if (is_gate) {                               // x-part kt 0..7 (prefetched)
      #pragma unroll
      for (int kt = 0; kt < 8; ++kt) {
        short8 b = bx_pf[kt];
        acc0 = __builtin_amdgcn_mfma_f32_16x16x32_bf16(areg[kt], b, acc0, 0,0,0);
        acc1 = __builtin_amdgcn_mfma_f32_16x16x32_bf16(s_odd[kt][half][lane], b, acc1, 0,0,0);
      }
    }
    #pragma unroll                               // h-part kt 8..39
    for (int kt = 8; kt < NKT; ++kt) {
      short8 b  = Bh[((kt-8)*4 + ct)*64 + lane];
      short8 ae = (kt < 28) ? areg[kt] : s_et[kt-28][half][lane];
      acc0 = __builtin_amdgcn_mfma_f32_16x16x32_bf16(ae, b, acc0, 0,0,0);
      acc1 = __builtin_amdgcn_mfma_f32_16x16x32_bf16(s_odd[kt][half][lane], b, acc1, 0,0,0);
    }

    if (is_gate) {
      #pragma unroll
      for (int e = 0; e < 2; ++e) {
        f32x4 acc = e ? acc1 : acc0;
        float zf = acc[0] + bfr[e], zi = acc[1] + bir[e];
        float zo = acc[2] + bor[e], zc = acc[3] + bcr[e];
        float fg = sigm(zf), ig = sigm(zi), og = sigm(zo);
        float chh = tanh_fast(zc);
        float cold = e ? c1 : c0;
        float cn = fg*cold + ig*chh;
        if (e) c1 = cn; else c0 = cn;
        float hn = og*tanh_fast(cn);
        if (s == S_LENN-1) { hf[hh2[e]*B_SZZ + col] = hn;
                             cbuf[hh2[e]*B_SZZ + col] = cn; }
        hwr[hoff[e]] = f2bf(hn);
      }
      if (s + 1 < S_LENN) {                      // prefetch next x under barrier
        const short8* B0 = (const short8*)Bx + (size_t)(s+1)*8*4*64;
        #pragma unroll
        for (int kt = 0; kt < 8; ++kt)
          bx_pf[kt] = B0[(kt*4 + ct)*64 + lane];
      }
    } else if (s > 0) {                          // fc rows -> logits col s-1
      #pragma unroll
      for (int e = 0; e < 2; ++e) {
        f32x4 acc = e ? acc1 : acc0;
        int mt = 2*half + e;
        #pragma unroll
        for (int r = 0; r < 4; ++r) {
          int o = (t-64)*64 + mt*16 + 4*(lane>>4) + r;
          out[(size_t)o*SBB + (size_t)(s-1)*B_SZZ + col] = acc[r] + fcbr[e][r];
        }
      }
    }

    if (s < S_LENN) {                            // device barrier (one/step)
      __threadfence();
      __syncthreads();
      if (tid == 0) {
        unsigned ls = (unsigned)((s & 1) ^ 1);   // expected sense after bar s
        unsigned prev = __hip_atomic_fetch_add(&bar[0], 1u,
                           __ATOMIC_ACQ_REL, __HIP_MEMORY_SCOPE_AGENT);
        if (prev == NTILE - 1) {
          __hip_atomic_store(&bar[0], 0u,
                             __ATOMIC_RELAXED, __HIP_MEMORY_SCOPE_AGENT);
          __hip_atomic_store(&bar[16], ls,
                             __ATOMIC_RELEASE, __HIP_MEMORY_SCOPE_AGENT);
        } else {
          while (__hip_atomic_load(&bar[16],
                   __ATOMIC_ACQUIRE, __HIP_MEMORY_SCOPE_AGENT) != ls)
            __builtin_amdgcn_s_sleep(1);
        }
      }
      __syncthreads();
    }
  }
}

// in-place softmax over o for each (s,b) column
__global__ __launch_bounds__(256) void softmax_kernel(float* __restrict__ out)
{
  const int col = blockIdx.x*256 + threadIdx.x;
  float m = -1e30f, l = 0.f;
  for (int o = 0; o < O_DIMM; ++o) {
    float x  = out[(size_t)o*SBB + col];
    float mn = fmaxf(m, x);
    l = l*__expf(m - mn) + __expf(x - mn);
    m = mn;
  }
  const float inv = 1.f / l;
  for (int o = 0; o < O_DIMM; ++o) {
    float x = out[(size_t)o*SBB + col];
    out[(size_t)o*SBB + col] = __expf(x - m) * inv;
  }
}

__global__ __launch_bounds__(256) void tail_kernel(
    const float* __restrict__ h, const float* __restrict__ c,
    float* __restrict__ out)
{
  const int i = blockIdx.x*256 + threadIdx.x;     // 65536 each
  out[(size_t)O_DIMM*SBB + i]                = h[i];
  out[(size_t)O_DIMM*SBB + H_DIMM*B_SZZ + i] = c[i];
}

extern "C" void kernel_launch(void* const* d_in, const int* in_sizes, int n_in,
                              void* d_out, int out_size, void* d_ws, size_t ws_size,
                              hipStream_t stream) {
  const float* X   = (const float*)d_in[0];
  const float* Wf  = (const float*)d_in[1];
  const float* Wi  = (const float*)d_in[2];
  const float* Wo  = (const float*)d_in[3];
  const float* Wc  = (const float*)d_in[4];
  const float* Uf  = (const float*)d_in[5];
  const float* Ui  = (const float*)d_in[6];
  const float* Uo  = (const float*)d_in[7];
  const float* Uc  = (const float*)d_in[8];
  const float* bf  = (const float*)d_in[9];
  const float* bi  = (const float*)d_in[10];
  const float* bo  = (const float*)d_in[11];
  const float* bc  = (const float*)d_in[12];
  const float* fcw = (const float*)d_in[13];
  const float* fcb = (const float*)d_in[14];
  float* out = (float*)d_out;

  char* ws = (char*)d_ws;
  unsigned short* A_bf = (unsigned short*)(ws + OFF_ABF);
  unsigned short* Bx   = (unsigned short*)(ws + OFF_BX);
  unsigned short* hb0  = (unsigned short*)(ws + OFF_HB0);
  unsigned short* hb1  = (unsigned short*)(ws + OFF_HB1);
  unsigned short* hb2  = (unsigned short*)(ws + OFF_HB2);
  float* cb = (float*)(ws + OFF_C);
  float* hf = (float*)(ws + OFF_HF);
  unsigned* bar = (unsigned*)(ws + OFF_BAR);

  // ws re-poisoned 0xAA before every timed call: rebuild state every call
  hipMemsetAsync(hb0, 0, 131072, stream);          // h_{-1} = 0
  hipMemsetAsync(bar, 0, 128, stream);             // barrier cnt + sense
  prep_w<<<2720, 256, 0, stream>>>(Wf, Wi, Wo, Wc, Uf, Ui, Uo, Uc, fcw, A_bf);
  prep_x<<<4096, 256, 0, stream>>>(X, Bx);

  lstm_persist<<<NTILE, 512, 0, stream>>>(
      A_bf, Bx, hb0, hb1, hb2, bf, bi, bo, bc, fcb, cb, hf, out, bar);

  softmax_kernel<<<SBB/256, 256, 0, stream>>>(out);
  tail_kernel<<<H_DIMM*B_SZZ/256, 256, 0, stream>>>(hf, cb, out);
}

// Round 6
// 5263.343 us; speedup vs baseline: 2.3566x; 2.3566x over previous
//
#include <hip/hip_runtime.h>

#define I_DIMM 256
#define H_DIMM 1024
#define O_DIMM 256
#define S_LENN 512
#define B_SZZ  64
#define SBB    (S_LENN*B_SZZ)      // 32768
#define NKT    40                  // k-tiles of 32 over K=1280
#define NTILE  68                  // 64 gate tiles + 4 fc tiles (64 rows each)

typedef float f32x4  __attribute__((ext_vector_type(4)));
typedef short short8 __attribute__((ext_vector_type(8)));
union UNI { unsigned long long q2[2]; short8 v; };

// ws layout (bytes):
#define OFF_ABF 0u                  // A frags: 68*40*4*64*16 = 11,141,120
#define OFF_BX  11141120u           // X frags: 512*8*4*64*16 = 16,777,216
#define OFF_HB0 27918336u           // h frag bufs x3: 131,072 each
#define OFF_HB1 28049408u
#define OFF_HB2 28180480u
#define OFF_C   28311552u           // c state f32: 262,144
#define OFF_HF  28573696u           // final h f32: 262,144
#define OFF_BAR 28835840u           // barrier: monotonic counter

__device__ __forceinline__ float sigm(float x){ return 1.f/(1.f+__expf(-x)); }
__device__ __forceinline__ float tanh_fast(float x){
  x = fminf(fmaxf(x,-15.f),15.f);
  float e = __expf(2.f*x);
  return (e-1.f)/(e+1.f);
}
__device__ __forceinline__ unsigned f2bf(float x){
  unsigned u = __float_as_uint(x);
  u += 0x7FFFu + ((u>>16)&1u);            // RNE
  return u >> 16;
}

// ---- pack weights into A-fragment layout (once per launch) ----
__global__ __launch_bounds__(256) void prep_w(
    const float* __restrict__ Wf, const float* __restrict__ Wi,
    const float* __restrict__ Wo, const float* __restrict__ Wc,
    const float* __restrict__ Uf, const float* __restrict__ Ui,
    const float* __restrict__ Uo, const float* __restrict__ Uc,
    const float* __restrict__ fcw, unsigned short* __restrict__ A_bf)
{
  int u = blockIdx.x*256 + threadIdx.x;          // 0 .. 696319
  int lane = u & 63;
  int mt   = (u >> 6) & 3;
  int kt   = (u >> 8) % NKT;
  int tile = u / (NKT*4*64);
  int r16  = lane & 15;
  int kb   = kt*32 + (lane>>4)*8;
  short8 v;
  if (tile < 64) {
    int zrow = tile*64 + mt*16 + r16;
    int h = zrow >> 2, g = zrow & 3;
    const float* Ws = (g==0)?Wf:(g==1)?Wi:(g==2)?Wo:Wc;
    const float* Us = (g==0)?Uf:(g==1)?Ui:(g==2)?Uo:Uc;
    #pragma unroll
    for (int j = 0; j < 8; ++j) {
      int k = kb + j;
      float x = (k < I_DIMM) ? Ws[h*I_DIMM + k] : Us[h*H_DIMM + (k - I_DIMM)];
      v[j] = (short)f2bf(x);
    }
  } else {
    int o = (tile-64)*64 + mt*16 + r16;
    #pragma unroll
    for (int j = 0; j < 8; ++j) {
      int k = kb + j;
      v[j] = (short)((k < I_DIMM) ? 0 : f2bf(fcw[o*H_DIMM + (k - I_DIMM)]));
    }
  }
  *(short8*)(A_bf + (size_t)u*8) = v;
}

// ---- pack X into B-fragment layout for all steps (once per launch) ----
__global__ __launch_bounds__(256) void prep_x(
    const float* __restrict__ X, unsigned short* __restrict__ Bx)
{
  int u = blockIdx.x*256 + threadIdx.x;          // 0 .. 1048575
  int lane = u & 63;
  int ct   = (u >> 6) & 3;
  int kt   = (u >> 8) & 7;
  int s    = u >> 11;
  int col  = ct*16 + (lane & 15);
  int kb   = kt*32 + (lane>>4)*8;
  short8 v;
  #pragma unroll
  for (int j = 0; j < 8; ++j)
    v[j] = (short)f2bf(X[(size_t)(kb + j)*SBB + s*B_SZZ + col]);
  *(short8*)(Bx + (size_t)u*8) = v;
}

#define ALOAD(P) __hip_atomic_load((P), __ATOMIC_RELAXED, __HIP_MEMORY_SCOPE_AGENT)
#define ASTORE(P,V) __hip_atomic_store((P), (V), __ATOMIC_RELAXED, __HIP_MEMORY_SCOPE_AGENT)

// load 4 kt-frags (8 qwords) of h via LLC-coherent relaxed atomics
#define LD4(KT0, DST) { _Pragma("unroll") \
  for (int q = 0; q < 4; ++q) { \
    size_t fi = ((size_t)((KT0) + q - 8)*4 + ct)*64 + lane; \
    DST[2*q]   = ALOAD(Bq + 2*fi); \
    DST[2*q+1] = ALOAD(Bq + 2*fi + 1); } }

// consume 4 kt-frags: 2 MFMAs each (even-mt from areg/s_et, odd-mt from s_odd)
#define USE4(KT0, SRC) { _Pragma("unroll") \
  for (int q = 0; q < 4; ++q) { \
    UNI u_; u_.q2[0] = SRC[2*q]; u_.q2[1] = SRC[2*q+1]; \
    const int kt_ = (KT0) + q; \
    short8 ae_ = (kt_ < 28) ? areg[kt_] : s_et[kt_-28][half][lane]; \
    acc0 = __builtin_amdgcn_mfma_f32_16x16x32_bf16(ae_, u_.v, acc0, 0,0,0); \
    acc1 = __builtin_amdgcn_mfma_f32_16x16x32_bf16(s_odd[kt_][half][lane], u_.v, acc1, 0,0,0); } }

// ---- persistent kernel: all 512 steps in one dispatch ----
// 68 blocks x 512 thr. Wave w: ct=w&3, half=w>>2 -> mt {2half, 2half+1}.
// h exchange via LLC (sc1 relaxed atomics): NO L2 flushes. Monotonic barrier.
__global__ __launch_bounds__(512, 2) void lstm_persist(
    const unsigned short* __restrict__ A_bf,
    const unsigned short* __restrict__ Bx,
    unsigned short* __restrict__ hbuf0,
    unsigned short* __restrict__ hbuf1,
    unsigned short* __restrict__ hbuf2,
    const float* __restrict__ bfp, const float* __restrict__ bip,
    const float* __restrict__ bop, const float* __restrict__ bcp,
    const float* __restrict__ fcb,
    float* __restrict__ cbuf, float* __restrict__ hf,
    float* __restrict__ out, unsigned* __restrict__ bar)
{
  __shared__ short8 s_odd[NKT][2][64];   // odd-mt frags, all kt   (80 KB)
  __shared__ short8 s_et [12][2][64];    // even-mt frags, kt>=28  (24 KB)

  const int t    = blockIdx.x;
  const int tid  = threadIdx.x;
  const int lane = tid & 63;
  const int w    = tid >> 6;
  const int ct   = w & 3;
  const int half = w >> 2;
  const bool is_gate = (t < 64);
  const int col  = ct*16 + (lane & 15);
  const int r    = lane >> 4;            // 0..3

  const short8* Af = (const short8*)A_bf + (size_t)t*NKT*4*64;

  for (int i = tid; i < 104*64; i += 512) {
    int a = i >> 6, l = i & 63;
    if (a < 80) { int kt = a >> 1, hh = a & 1;
      s_odd[kt][hh][l] = Af[(kt*4 + 2*hh + 1)*64 + l];
    } else { int e = a - 80; int kt = 28 + (e >> 1), hh = e & 1;
      s_et[kt-28][hh][l] = Af[(kt*4 + 2*hh)*64 + l];
    }
  }
  short8 areg[28];
  #pragma unroll
  for (int kt = 0; kt < 28; ++kt)
    areg[kt] = Af[(kt*4 + 2*half)*64 + lane];
  __syncthreads();

  // s-invariant epilogue constants
  const int h0 = t*16 + 8*half + r;                 // e=0 row; e=1 is h0+4
  const int kl0 = h0 & 31;
  const size_t fragidx = ((size_t)(h0>>5)*4 + ct)*64
                         + (((kl0>>3)<<4) | (lane & 15));
  float bfr[2], bir[2], bor[2], bcr[2], fcbr[2][4];
  #pragma unroll
  for (int e = 0; e < 2; ++e) {
    int hh = h0 + 4*e;
    if (is_gate) { bfr[e]=bfp[hh]; bir[e]=bip[hh]; bor[e]=bop[hh]; bcr[e]=bcp[hh]; }
    else {
      int mt = 2*half + e;
      #pragma unroll
      for (int q = 0; q < 4; ++q)
        fcbr[e][q] = fcb[(t-64)*64 + mt*16 + 4*r + q];
    }
  }

  unsigned short* hbs[3] = {hbuf0, hbuf1, hbuf2};
  float c0 = 0.f, c1 = 0.f;

  short8 bx_pf[8];
  if (is_gate) {
    #pragma unroll
    for (int kt = 0; kt < 8; ++kt)
      bx_pf[kt] = ((const short8*)Bx)[(kt*4 + ct)*64 + lane];
  }

  #pragma unroll 1
  for (int s = 0; s <= S_LENN; ++s) {
    const bool compute = is_gate ? (s < S_LENN) : (s > 0);
    if (compute) {
      f32x4 acc0 = {0.f,0.f,0.f,0.f}, acc1 = {0.f,0.f,0.f,0.f};
      if (is_gate) {
        #pragma unroll
        for (int kt = 0; kt < 8; ++kt) {
          short8 b = bx_pf[kt];
          acc0 = __builtin_amdgcn_mfma_f32_16x16x32_bf16(areg[kt], b, acc0, 0,0,0);
          acc1 = __builtin_amdgcn_mfma_f32_16x16x32_bf16(s_odd[kt][half][lane], b, acc1, 0,0,0);
        }
      }
      // h-part kt 8..39: LLC-coherent loads, 2 groups in flight
      const unsigned long long* Bq = (const unsigned long long*)hbs[s % 3];
      unsigned long long A0[8], A1[8];
      LD4(8,  A0);
      LD4(12, A1); USE4(8,  A0);
      LD4(16, A0); USE4(12, A1);
      LD4(20, A1); USE4(16, A0);
      LD4(24, A0); USE4(20, A1);
      LD4(28, A1); USE4(24, A0);
      LD4(32, A0); USE4(28, A1);
      LD4(36, A1); USE4(32, A0);
      USE4(36, A1);

      if (is_gate) {
        float zf0 = acc0[0]+bfr[0], zi0 = acc0[1]+bir[0];
        float zo0 = acc0[2]+bor[0], zc0 = acc0[3]+bcr[0];
        float fg0 = sigm(zf0), ig0 = sigm(zi0), og0 = sigm(zo0);
        float cn0 = fg0*c0 + ig0*tanh_fast(zc0);  c0 = cn0;
        float hn0 = og0*tanh_fast(cn0);
        float zf1 = acc1[0]+bfr[1], zi1 = acc1[1]+bir[1];
        float zo1 = acc1[2]+bor[1], zc1 = acc1[3]+bcr[1];
        float fg1 = sigm(zf1), ig1 = sigm(zi1), og1 = sigm(zo1);
        float cn1 = fg1*c1 + ig1*tanh_fast(zc1);  c1 = cn1;
        float hn1 = og1*tanh_fast(cn1);
        if (s == S_LENN-1) {
          hf[h0*B_SZZ + col]       = hn0;  cbuf[h0*B_SZZ + col]       = cn0;
          hf[(h0+4)*B_SZZ + col]   = hn1;  cbuf[(h0+4)*B_SZZ + col]   = cn1;
        }
        unsigned v0 = f2bf(hn0), v1 = f2bf(hn1);
        unsigned p0 = (unsigned)__shfl_xor((int)v0, 16);
        unsigned p1 = (unsigned)__shfl_xor((int)v1, 16);
        unsigned* Hw = (unsigned*)hbs[(s + 1) % 3];
        if ((r & 1) == 0) {                    // elem pairs (r,r+1),(r+4,r+5)
          ASTORE(Hw + fragidx*4 + (r>>1),     v0 | (p0 << 16));
          ASTORE(Hw + fragidx*4 + (r>>1) + 2, v1 | (p1 << 16));
        }
      } else {
        #pragma unroll
        for (int e = 0; e < 2; ++e) {
          f32x4 acc = e ? acc1 : acc0;
          int mt = 2*half + e;
          #pragma unroll
          for (int q = 0; q < 4; ++q) {
            int o = (t-64)*64 + mt*16 + 4*r + q;
            out[(size_t)o*SBB + (size_t)(s-1)*B_SZZ + col] = acc[q] + fcbr[e][q];
          }
        }
      }
    }

    if (s < S_LENN) {
      asm volatile("s_waitcnt vmcnt(0)" ::: "memory");  // h stores at LLC
      __syncthreads();
      if (is_gate && s + 1 < S_LENN) {                  // x-prefetch under spin
        const short8* B0 = (const short8*)Bx + (size_t)(s+1)*2048;
        #pragma unroll
        for (int kt = 0; kt < 8; ++kt)
          bx_pf[kt] = B0[(kt*4 + ct)*64 + lane];
      }
      if (tid == 0) {
        __hip_atomic_fetch_add(bar, 1u, __ATOMIC_RELAXED, __HIP_MEMORY_SCOPE_AGENT);
        const unsigned tgt = (unsigned)(s + 1) * NTILE;
        while (ALOAD(bar) < tgt) __builtin_amdgcn_s_sleep(2);
      }
      __syncthreads();
      asm volatile("" ::: "memory");
    }
  }
}

// in-place softmax over o for each (s,b) column
__global__ __launch_bounds__(256) void softmax_kernel(float* __restrict__ out)
{
  const int col = blockIdx.x*256 + threadIdx.x;
  float m = -1e30f, l = 0.f;
  for (int o = 0; o < O_DIMM; ++o) {
    float x  = out[(size_t)o*SBB + col];
    float mn = fmaxf(m, x);
    l = l*__expf(m - mn) + __expf(x - mn);
    m = mn;
  }
  const float inv = 1.f / l;
  for (int o = 0; o < O_DIMM; ++o) {
    float x = out[(size_t)o*SBB + col];
    out[(size_t)o*SBB + col] = __expf(x - m) * inv;
  }
}

__global__ __launch_bounds__(256) void tail_kernel(
    const float* __restrict__ h, const float* __restrict__ c,
    float* __restrict__ out)
{
  const int i = blockIdx.x*256 + threadIdx.x;     // 65536 each
  out[(size_t)O_DIMM*SBB + i]                = h[i];
  out[(size_t)O_DIMM*SBB + H_DIMM*B_SZZ + i] = c[i];
}

extern "C" void kernel_launch(void* const* d_in, const int* in_sizes, int n_in,
                              void* d_out, int out_size, void* d_ws, size_t ws_size,
                              hipStream_t stream) {
  const float* X   = (const float*)d_in[0];
  const float* Wf  = (const float*)d_in[1];
  const float* Wi  = (const float*)d_in[2];
  const float* Wo  = (const float*)d_in[3];
  const float* Wc  = (const float*)d_in[4];
  const float* Uf  = (const float*)d_in[5];
  const float* Ui  = (const float*)d_in[6];
  const float* Uo  = (const float*)d_in[7];
  const float* Uc  = (const float*)d_in[8];
  const float* bf  = (const float*)d_in[9];
  const float* bi  = (const float*)d_in[10];
  const float* bo  = (const float*)d_in[11];
  const float* bc  = (const float*)d_in[12];
  const float* fcw = (const float*)d_in[13];
  const float* fcb = (const float*)d_in[14];
  float* out = (float*)d_out;

  char* ws = (char*)d_ws;
  unsigned short* A_bf = (unsigned short*)(ws + OFF_ABF);
  unsigned short* Bx   = (unsigned short*)(ws + OFF_BX);
  unsigned short* hb0  = (unsigned short*)(ws + OFF_HB0);
  unsigned short* hb1  = (unsigned short*)(ws + OFF_HB1);
  unsigned short* hb2  = (unsigned short*)(ws + OFF_HB2);
  float* cb = (float*)(ws + OFF_C);
  float* hf = (float*)(ws + OFF_HF);
  unsigned* bar = (unsigned*)(ws + OFF_BAR);

  // ws re-poisoned 0xAA before every timed call: rebuild state every call
  hipMemsetAsync(hb0, 0, 131072, stream);          // h_{-1} = 0
  hipMemsetAsync(bar, 0, 128, stream);             // monotonic barrier counter
  prep_w<<<2720, 256, 0, stream>>>(Wf, Wi, Wo, Wc, Uf, Ui, Uo, Uc, fcw, A_bf);
  prep_x<<<4096, 256, 0, stream>>>(X, Bx);

  lstm_persist<<<NTILE, 512, 0, stream>>>(
      A_bf, Bx, hb0, hb1, hb2, bf, bi, bo, bc, fcb, cb, hf, out, bar);

  softmax_kernel<<<SBB/256, 256, 0, stream>>>(out);
  tail_kernel<<<H_DIMM*B_SZZ/256, 256, 0, stream>>>(hf, cb, out);
}

// Round 8
// 3710.679 us; speedup vs baseline: 3.3427x; 1.4184x over previous
//
#include <hip/hip_runtime.h>

#define I_DIMM 256
#define H_DIMM 1024
#define O_DIMM 256
#define S_LENN 512
#define B_SZZ  64
#define SBB    (S_LENN*B_SZZ)      // 32768
#define NKT    40                  // k-tiles of 32 over K=1280
#define NBLK   136                 // 128 gate blocks + 8 fc blocks
#define NMT    272                 // 272 m-tiles of 16 rows (256 gate + 16 fc)

typedef float f32x4  __attribute__((ext_vector_type(4)));
typedef short short8 __attribute__((ext_vector_type(8)));
union UNI { unsigned long long q2[2]; short8 v; };

// ws layout (bytes):
#define OFF_ABF 0u                  // A frags: 272*40*64*16 = 11,141,120
#define OFF_BX  11141120u           // X frags: 512*8*4*64*16 = 16,777,216
#define OFF_HB0 27918336u           // h frag bufs x3: 131,072 each
#define OFF_HB1 28049408u
#define OFF_HB2 28180480u
#define OFF_C   28311552u           // c state f32: 262,144
#define OFF_HF  28573696u           // final h f32: 262,144
#define OFF_BAR 28835840u           // per-block flags, 128B apart (17,408 B)

__device__ __forceinline__ float sigm(float x){ return 1.f/(1.f+__expf(-x)); }
__device__ __forceinline__ float tanh_fast(float x){
  x = fminf(fmaxf(x,-15.f),15.f);
  float e = __expf(2.f*x);
  return (e-1.f)/(e+1.f);
}
__device__ __forceinline__ unsigned f2bf(float x){
  unsigned u = __float_as_uint(x);
  u += 0x7FFFu + ((u>>16)&1u);            // RNE
  return u >> 16;
}

// ---- pack weights into A-fragment layout, mtile-major (once per launch) ----
// frag u = (mtile*40 + kt)*64 + lane; elem j: k = kt*32+(lane>>4)*8+j.
// mtile 0..255: z-row = mtile*16 + (lane&15) = 4h+g. mtile 256..271: fc row.
__global__ __launch_bounds__(256) void prep_w(
    const float* __restrict__ Wf, const float* __restrict__ Wi,
    const float* __restrict__ Wo, const float* __restrict__ Wc,
    const float* __restrict__ Uf, const float* __restrict__ Ui,
    const float* __restrict__ Uo, const float* __restrict__ Uc,
    const float* __restrict__ fcw, unsigned short* __restrict__ A_bf)
{
  int u = blockIdx.x*256 + threadIdx.x;          // 0 .. 696319
  int lane  = u & 63;
  int kt    = (u >> 6) % NKT;
  int mtile = u / (NKT*64);
  int r16   = lane & 15;
  int kb    = kt*32 + (lane>>4)*8;
  short8 v;
  if (mtile < 256) {
    int zrow = mtile*16 + r16;
    int h = zrow >> 2, g = zrow & 3;
    const float* Ws = (g==0)?Wf:(g==1)?Wi:(g==2)?Wo:Wc;
    const float* Us = (g==0)?Uf:(g==1)?Ui:(g==2)?Uo:Uc;
    #pragma unroll
    for (int j = 0; j < 8; ++j) {
      int k = kb + j;
      float x = (k < I_DIMM) ? Ws[h*I_DIMM + k] : Us[h*H_DIMM + (k - I_DIMM)];
      v[j] = (short)f2bf(x);
    }
  } else {
    int o = (mtile - 256)*16 + r16;
    #pragma unroll
    for (int j = 0; j < 8; ++j) {
      int k = kb + j;
      v[j] = (short)((k < I_DIMM) ? 0 : (short)f2bf(fcw[o*H_DIMM + (k - I_DIMM)]));
    }
  }
  *(short8*)(A_bf + (size_t)u*8) = v;
}

// ---- pack X into B-fragment layout for all steps (once per launch) ----
__global__ __launch_bounds__(256) void prep_x(
    const float* __restrict__ X, unsigned short* __restrict__ Bx)
{
  int u = blockIdx.x*256 + threadIdx.x;          // 0 .. 1048575
  int lane = u & 63;
  int ct   = (u >> 6) & 3;
  int kt   = (u >> 8) & 7;
  int s    = u >> 11;
  int col  = ct*16 + (lane & 15);
  int kb   = kt*32 + (lane>>4)*8;
  short8 v;
  #pragma unroll
  for (int j = 0; j < 8; ++j)
    v[j] = (short)f2bf(X[(size_t)(kb + j)*SBB + s*B_SZZ + col]);
  *(short8*)(Bx + (size_t)u*8) = v;
}

#define ALOAD(P) __hip_atomic_load((P), __ATOMIC_RELAXED, __HIP_MEMORY_SCOPE_AGENT)
#define ASTORE(P,V) __hip_atomic_store((P), (V), __ATOMIC_RELAXED, __HIP_MEMORY_SCOPE_AGENT)

// load 4 kt-frags (8 qwords) of h via LLC-coherent relaxed atomics
#define LD4(KT0, DST) { _Pragma("unroll") \
  for (int q = 0; q < 4; ++q) { \
    size_t fi = ((size_t)((KT0) + q - 8)*4 + ct)*64 + lane; \
    DST[2*q]   = ALOAD(Bq + 2*fi); \
    DST[2*q+1] = ALOAD(Bq + 2*fi + 1); } }

// consume 4 kt-frags: 1 MFMA each (A from registers)
#define USE4(KT0, SRC) { _Pragma("unroll") \
  for (int q = 0; q < 4; ++q) { \
    UNI u_; u_.q2[0] = SRC[2*q]; u_.q2[1] = SRC[2*q+1]; \
    acc = __builtin_amdgcn_mfma_f32_16x16x32_bf16(areg[(KT0) + q - 8], u_.v, acc, 0,0,0); } }

// ---- persistent kernel: all 512 steps in one dispatch ----
// 136 blocks x 512 thr (8 waves). Wave w: ct=w&3, mt=w>>2 -> one 16-row
// m-tile x 16 cols. U-part A-frags all in registers (areg[32]); x-part W in
// LDS. h exchange via LLC relaxed atomics; flag-array barrier, parallel poll.
__global__ __launch_bounds__(512, 2) void lstm_persist(
    const unsigned short* __restrict__ A_bf,
    const unsigned short* __restrict__ Bx,
    unsigned short* __restrict__ hbuf0,
    unsigned short* __restrict__ hbuf1,
    unsigned short* __restrict__ hbuf2,
    const float* __restrict__ bfp, const float* __restrict__ bip,
    const float* __restrict__ bop, const float* __restrict__ bcp,
    const float* __restrict__ fcb,
    float* __restrict__ cbuf, float* __restrict__ hf,
    float* __restrict__ out, unsigned* __restrict__ flags)
{
  __shared__ short8 s_ax[2][8][64];      // x-part W frags (16 KB, gate blocks)

  const int t    = blockIdx.x;
  const int tid  = threadIdx.x;
  const int lane = tid & 63;
  const int w    = __builtin_amdgcn_readfirstlane(tid >> 6);
  const int ct   = w & 3;
  const int mt   = w >> 2;               // 0..1
  const bool is_gate = (t < 128);
  const int col  = ct*16 + (lane & 15);
  const int r    = lane >> 4;            // 0..3
  const int mtile = is_gate ? (2*t + mt) : (256 + 2*(t - 128) + mt);

  const short8* Af = (const short8*)A_bf;

  if (is_gate) {
    for (int i = tid; i < 1024; i += 512) {      // 2 mt x 8 kt x 64 lanes
      int mtt = i >> 9, kt = (i >> 6) & 7, l = i & 63;
      s_ax[mtt][kt][l] = Af[((size_t)(2*t + mtt)*NKT + kt)*64 + l];
    }
  }
  short8 areg[32];                                // U-part A frags (128 VGPR)
  #pragma unroll
  for (int kt = 8; kt < NKT; ++kt)
    areg[kt-8] = Af[((size_t)mtile*NKT + kt)*64 + lane];
  __syncthreads();

  // s-invariant epilogue constants
  const int h0 = 8*t + 4*mt + r;                  // gate h row (gate blocks)
  const int kl = h0 & 31;
  const size_t fragidx = ((size_t)(h0>>5)*4 + ct)*64
                         + (((kl>>3)<<4) | (lane & 15));
  const int word = (kl >> 1) & 3;
  float bfr=0, bir=0, bor=0, bcr=0; float fcbr[4]; int obase=0;
  if (is_gate) { bfr=bfp[h0]; bir=bip[h0]; bor=bop[h0]; bcr=bcp[h0]; }
  else {
    obase = (mtile - 256)*16 + 4*r;
    #pragma unroll
    for (int q = 0; q < 4; ++q) fcbr[q] = fcb[obase + q];
  }

  unsigned short* hbs[3] = {hbuf0, hbuf1, hbuf2};
  float c0 = 0.f;

  short8 bx_pf[8];
  if (is_gate) {
    #pragma unroll
    for (int kt = 0; kt < 8; ++kt)
      bx_pf[kt] = ((const short8*)Bx)[(kt*4 + ct)*64 + lane];
  }

  #pragma unroll 1
  for (int s = 0; s <= S_LENN; ++s) {
    const bool compute = is_gate ? (s < S_LENN) : (s > 0);
    if (compute) {
      f32x4 acc = {0.f,0.f,0.f,0.f};
      const unsigned long long* Bq = (const unsigned long long*)hbs[s % 3];
      unsigned long long A0[8], A1[8], A2[8];
      LD4(8, A0); LD4(12, A1);                    // start h stream early
      if (is_gate) {                              // x-part under load latency
        #pragma unroll
        for (int kt = 0; kt < 8; ++kt)
          acc = __builtin_amdgcn_mfma_f32_16x16x32_bf16(
                    s_ax[mt][kt][lane], bx_pf[kt], acc, 0,0,0);
      }
      LD4(16, A2); USE4(8,  A0); LD4(20, A0);
      USE4(12, A1); LD4(24, A1);
      USE4(16, A2); LD4(28, A2);
      USE4(20, A0); LD4(32, A0);
      USE4(24, A1); LD4(36, A1);
      USE4(28, A2);
      USE4(32, A0);
      USE4(36, A1);

      if (is_gate) {
        float zf = acc[0]+bfr, zi = acc[1]+bir, zo = acc[2]+bor, zc = acc[3]+bcr;
        float fg = sigm(zf), ig = sigm(zi), og = sigm(zo);
        float cn = fg*c0 + ig*tanh_fast(zc);  c0 = cn;
        float hn = og*tanh_fast(cn);
        if (s == S_LENN-1) { hf[h0*B_SZZ + col] = hn; cbuf[h0*B_SZZ + col] = cn; }
        unsigned v0 = f2bf(hn);
        unsigned p0 = (unsigned)__shfl_xor((int)v0, 16);   // partner row h0^1
        unsigned* Hw = (unsigned*)hbs[(s + 1) % 3];
        if ((r & 1) == 0)
          ASTORE(Hw + fragidx*4 + word, v0 | (p0 << 16));
      } else {
        #pragma unroll
        for (int q = 0; q < 4; ++q)
          out[(size_t)(obase + q)*SBB + (size_t)(s-1)*B_SZZ + col]
              = acc[q] + fcbr[q];
      }
    }

    if (s < S_LENN) {
      asm volatile("s_waitcnt vmcnt(0)" ::: "memory");   // h stores at LLC
      __syncthreads();                                   // all waves drained
      if (tid == 0) ASTORE(flags + (size_t)t*32, (unsigned)(s + 1));
      if (is_gate && s + 1 < S_LENN) {                   // x-prefetch s+1
        const short8* B0 = (const short8*)Bx + (size_t)(s+1)*2048;
        #pragma unroll
        for (int kt = 0; kt < 8; ++kt)
          bx_pf[kt] = B0[(kt*4 + ct)*64 + lane];
      }
      if (w == 0) {                                      // parallel flag poll
        const unsigned tgt = (unsigned)(s + 1);
        bool done;
        do {
          unsigned a  = ALOAD(flags + lane*32);
          unsigned b2 = ALOAD(flags + (64 + lane)*32);
          unsigned c2 = (lane < 8) ? ALOAD(flags + (128 + lane)*32) : tgt;
          done = (a >= tgt) && (b2 >= tgt) && (c2 >= tgt);
        } while (!__all(done));
      }
      __syncthreads();
    }
  }
}

// in-place softmax over o for each (s,b) column
__global__ __launch_bounds__(256) void softmax_kernel(float* __restrict__ out)
{
  const int col = blockIdx.x*256 + threadIdx.x;
  float m = -1e30f, l = 0.f;
  for (int o = 0; o < O_DIMM; ++o) {
    float x  = out[(size_t)o*SBB + col];
    float mn = fmaxf(m, x);
    l = l*__expf(m - mn) + __expf(x - mn);
    m = mn;
  }
  const float inv = 1.f / l;
  for (int o = 0; o < O_DIMM; ++o) {
    float x = out[(size_t)o*SBB + col];
    out[(size_t)o*SBB + col] = __expf(x - m) * inv;
  }
}

__global__ __launch_bounds__(256) void tail_kernel(
    const float* __restrict__ h, const float* __restrict__ c,
    float* __restrict__ out)
{
  const int i = blockIdx.x*256 + threadIdx.x;     // 65536 each
  out[(size_t)O_DIMM*SBB + i]                = h[i];
  out[(size_t)O_DIMM*SBB + H_DIMM*B_SZZ + i] = c[i];
}

extern "C" void kernel_launch(void* const* d_in, const int* in_sizes, int n_in,
                              void* d_out, int out_size, void* d_ws, size_t ws_size,
                              hipStream_t stream) {
  const float* X   = (const float*)d_in[0];
  const float* Wf  = (const float*)d_in[1];
  const float* Wi  = (const float*)d_in[2];
  const float* Wo  = (const float*)d_in[3];
  const float* Wc  = (const float*)d_in[4];
  const float* Uf  = (const float*)d_in[5];
  const float* Ui  = (const float*)d_in[6];
  const float* Uo  = (const float*)d_in[7];
  const float* Uc  = (const float*)d_in[8];
  const float* bf  = (const float*)d_in[9];
  const float* bi  = (const float*)d_in[10];
  const float* bo  = (const float*)d_in[11];
  const float* bc  = (const float*)d_in[12];
  const float* fcw = (const float*)d_in[13];
  const float* fcb = (const float*)d_in[14];
  float* out = (float*)d_out;

  char* ws = (char*)d_ws;
  unsigned short* A_bf = (unsigned short*)(ws + OFF_ABF);
  unsigned short* Bx   = (unsigned short*)(ws + OFF_BX);
  unsigned short* hb0  = (unsigned short*)(ws + OFF_HB0);
  unsigned short* hb1  = (unsigned short*)(ws + OFF_HB1);
  unsigned short* hb2  = (unsigned short*)(ws + OFF_HB2);
  float* cb = (float*)(ws + OFF_C);
  float* hf = (float*)(ws + OFF_HF);
  unsigned* flags = (unsigned*)(ws + OFF_BAR);

  // ws re-poisoned 0xAA before every timed call: rebuild state every call
  hipMemsetAsync(hb0, 0, 131072, stream);          // h_{-1} = 0
  hipMemsetAsync(flags, 0, 32768, stream);         // barrier flags
  prep_w<<<2720, 256, 0, stream>>>(Wf, Wi, Wo, Wc, Uf, Ui, Uo, Uc, fcw, A_bf);
  prep_x<<<4096, 256, 0, stream>>>(X, Bx);

  lstm_persist<<<NBLK, 512, 0, stream>>>(
      A_bf, Bx, hb0, hb1, hb2, bf, bi, bo, bc, fcb, cb, hf, out, flags);

  softmax_kernel<<<SBB/256, 256, 0, stream>>>(out);
  tail_kernel<<<H_DIMM*B_SZZ/256, 256, 0, stream>>>(hf, cb, out);
}